// Round 7
// baseline (1133.612 us; speedup 1.0000x reference)
//
#include <hip/hip_runtime.h>

#define NN 50000
#define EE 500000
#define GG 64
#define IN_F 128
#define H_F 64
#define HEADS 4
#define OUT_F 326000
#define NEG 0.2f

// ---------------- embedding GEMM: h0 = x @ W_emb + b_emb ----------------
__global__ __launch_bounds__(256) void k_emb(const float* __restrict__ x,
                                             const float* __restrict__ Wemb,
                                             const float* __restrict__ bemb,
                                             float* __restrict__ h0) {
    __shared__ float wlds[IN_F * H_F];  // [k][c], 32 KB
    int t = threadIdx.x;
#pragma unroll
    for (int i = 0; i < (IN_F * H_F) / (4 * 256); ++i)
        ((float4*)wlds)[t + 256 * i] = ((const float4*)Wemb)[t + 256 * i];
    __syncthreads();

    int c = t & 63, sub = t >> 6;
    int n0 = __builtin_amdgcn_readfirstlane(blockIdx.x * 32 + sub * 8);
    float bv = bemb[c];

    if (n0 + 8 <= NN) {
        const float4* xr = (const float4*)(x + (size_t)n0 * IN_F);
        float acc[8] = {0.f, 0.f, 0.f, 0.f, 0.f, 0.f, 0.f, 0.f};
        for (int k4 = 0; k4 < IN_F / 4; ++k4) {
            float w0 = wlds[(4 * k4 + 0) * H_F + c];
            float w1 = wlds[(4 * k4 + 1) * H_F + c];
            float w2 = wlds[(4 * k4 + 2) * H_F + c];
            float w3 = wlds[(4 * k4 + 3) * H_F + c];
#pragma unroll
            for (int j = 0; j < 8; ++j) {
                float4 xv = xr[j * (IN_F / 4) + k4];
                acc[j] = fmaf(xv.x, w0,
                         fmaf(xv.y, w1,
                         fmaf(xv.z, w2,
                         fmaf(xv.w, w3, acc[j]))));
            }
        }
#pragma unroll
        for (int j = 0; j < 8; ++j)
            h0[(size_t)(n0 + j) * H_F + c] = acc[j] + bv;
    } else {
        for (int j = 0; j < 8; ++j) {
            int n = n0 + j;
            if (n >= NN) break;
            const float* xrow = x + (size_t)n * IN_F;
            float a = 0.f;
            for (int k = 0; k < IN_F; ++k) a += xrow[k] * wlds[k * H_F + c];
            h0[(size_t)n * H_F + c] = a + bv;
        }
    }
}

// ---------------- per-layer GEMM: k_emb pattern, full W in LDS ---------------
// 512 threads (8 waves), 64 KB LDS -> 2 blocks/CU = 16 waves/CU. Thread t:
// output col tc = t&255 (head hd = tc>>6, chan lane = tc&63); group grp = t>>8
// owns 32 nodes in 8-node batches (acc[8], LDS reads amortized 1:8 vs FMA,
// h rows as wave-uniform float4 broadcasts). No per-thread weight array ->
// nothing for the register allocator to evict (the r6 failure mode).
__global__ __launch_bounds__(512) void k_gemm_layer(const float* __restrict__ h,
                                                    const float* __restrict__ W,
                                                    const float* __restrict__ a_src,
                                                    const float* __restrict__ a_dst,
                                                    float* __restrict__ xbuf,
                                                    float* __restrict__ ls,
                                                    float* __restrict__ ld) {
    __shared__ float wlds[H_F * 256];   // [k][col], 64 KB
    int t = threadIdx.x;
    {
        const float4* W4 = (const float4*)W;
        float4* wl4 = (float4*)wlds;
#pragma unroll
        for (int i = 0; i < 8; ++i)     // 4096 float4 / 512 threads
            wl4[t + 512 * i] = W4[t + 512 * i];
    }
    int tc = t & 255, grp = t >> 8;
    int lane = tc & 63, hd = tc >> 6;
    float asv = a_src[tc], adv = a_dst[tc];
    __syncthreads();

    int base = blockIdx.x * 64 + grp * 32;
    for (int g = 0; g < 4; ++g) {
        int n0 = __builtin_amdgcn_readfirstlane(base + g * 8);
        if (n0 >= NN) break;            // NN%8==0 -> 8-node groups all-or-nothing
        const float4* hr = (const float4*)(h + (size_t)n0 * H_F);  // wave-uniform
        float acc[8] = {0.f, 0.f, 0.f, 0.f, 0.f, 0.f, 0.f, 0.f};
        for (int k4 = 0; k4 < H_F / 4; ++k4) {
            float w0 = wlds[(4 * k4 + 0) * 256 + tc];   // lane-consecutive: no conflict
            float w1 = wlds[(4 * k4 + 1) * 256 + tc];
            float w2 = wlds[(4 * k4 + 2) * 256 + tc];
            float w3 = wlds[(4 * k4 + 3) * 256 + tc];
#pragma unroll
            for (int j = 0; j < 8; ++j) {
                float4 hv = hr[j * (H_F / 4) + k4];     // uniform 16B broadcast
                acc[j] = fmaf(hv.x, w0,
                         fmaf(hv.y, w1,
                         fmaf(hv.z, w2,
                         fmaf(hv.w, w3, acc[j]))));
            }
        }
#pragma unroll
        for (int j = 0; j < 8; ++j) {
            int n = n0 + j;
            // transposed store [n][chan][head]; block covers full 1 KB rows
            xbuf[(size_t)n * (HEADS * H_F) + lane * 4 + hd] = acc[j];
            float vs = acc[j] * asv, vd = acc[j] * adv;
#pragma unroll
            for (int off = 32; off; off >>= 1) {
                vs += __shfl_xor(vs, off, 64);
                vd += __shfl_xor(vd, off, 64);
            }
            if (lane == 0) {
                ls[n * HEADS + hd] = vs;
                ld[n * HEADS + hd] = vd;
            }
        }
    }
}

__device__ __forceinline__ float lrelu_exp(float e) {
    e = (e > 0.f) ? e : NEG * e;
    return __expf(e);
}

__device__ __forceinline__ float4 lexp4(float4 s, float4 d) {
    float4 r;
    r.x = lrelu_exp(s.x + d.x);
    r.y = lrelu_exp(s.y + d.y);
    r.z = lrelu_exp(s.z + d.z);
    r.w = lrelu_exp(s.w + d.w);
    return r;
}

// ================= CSR build (once per launch; graph static across layers) ====
__global__ void k_count(const int* __restrict__ dst, int* __restrict__ cnt) {
    int i = blockIdx.x * blockDim.x + threadIdx.x;
    if (i >= EE + NN) return;
    int d = (i < EE) ? dst[i] : (i - EE);
    atomicAdd(&cnt[d], 1);
}

// single-block scan of cnt[NN] -> row/cursor (replaces 3-kernel scan chain)
#define CHUNK 49          // 1024 * 49 = 50176 >= NN
__global__ __launch_bounds__(1024) void k_scan_one(const int* __restrict__ cnt,
                                                   int* __restrict__ row,
                                                   int* __restrict__ cursor) {
    __shared__ int lds[1024];
    int t = threadIdx.x;
    int c0 = t * CHUNK;
    int c1 = c0 + CHUNK; if (c1 > NN) c1 = NN;
    int s = 0;
    for (int i = c0; i < c1; ++i) s += cnt[i];
    lds[t] = s;
    __syncthreads();
    for (int off = 1; off < 1024; off <<= 1) {
        int add = (t >= off) ? lds[t - off] : 0;
        __syncthreads();
        lds[t] += add;
        __syncthreads();
    }
    int run = (t > 0) ? lds[t - 1] : 0;
    for (int i = c0; i < c1; ++i) {
        row[i] = run;
        cursor[i] = run;
        run += cnt[i];
    }
    if (t == 0) row[NN] = EE + NN;
}

__global__ void k_scatter(const int* __restrict__ src, const int* __restrict__ dst,
                          int* __restrict__ cursor, int* __restrict__ csr_src) {
    int i = blockIdx.x * blockDim.x + threadIdx.x;
    if (i >= EE + NN) return;
    int s, d;
    if (i < EE) { s = src[i]; d = dst[i]; } else { s = d = i - EE; }
    int pos = atomicAdd(&cursor[d], 1);
    csr_src[pos] = s;
}

// ========== fused softmax + aggregation + bias + relu ========================
__global__ __launch_bounds__(256) void k_aggr_csr(const int* __restrict__ row,
                                                  const int* __restrict__ csr_src,
                                                  const float4* __restrict__ ls4,
                                                  const float4* __restrict__ ld4,
                                                  const float4* __restrict__ xb4,
                                                  const float* __restrict__ bias,
                                                  float* __restrict__ hout) {
    int t = threadIdx.x;
    int lane = t & 63, wv = t >> 6;
    int dA = blockIdx.x * 8 + wv * 2;       // NN = 50000 = 6250 * 8 exactly
    int dB = dA + 1;
    if (dA >= NN) return;
    int r0A = row[dA], r1A = row[dA + 1];
    int r0B = row[dB], r1B = row[dB + 1];
    float4 bldA = ld4[dA];
    float4 bldB = ld4[dB];
    float4 accA = {0.f, 0.f, 0.f, 0.f}, denA = {1e-16f, 1e-16f, 1e-16f, 1e-16f};
    float4 accB = {0.f, 0.f, 0.f, 0.f}, denB = {1e-16f, 1e-16f, 1e-16f, 1e-16f};

    int jA = r0A, jB = r0B;
    int sA = (jA < r1A) ? csr_src[jA] : 0;
    int sB = (jB < r1B) ? csr_src[jB] : 0;

    while (jA < r1A && jB < r1B) {
        int sa = __builtin_amdgcn_readfirstlane(sA);
        int sb = __builtin_amdgcn_readfirstlane(sB);
        float4 xa = xb4[(size_t)sa * H_F + lane];
        float4 xb = xb4[(size_t)sb * H_F + lane];
        float4 la = ls4[sa];
        float4 lb = ls4[sb];
        ++jA; if (jA < r1A) sA = csr_src[jA];
        ++jB; if (jB < r1B) sB = csr_src[jB];
        float4 ea = lexp4(la, bldA);
        float4 eb = lexp4(lb, bldB);
        denA.x += ea.x; denA.y += ea.y; denA.z += ea.z; denA.w += ea.w;
        denB.x += eb.x; denB.y += eb.y; denB.z += eb.z; denB.w += eb.w;
        accA.x = fmaf(ea.x, xa.x, accA.x);
        accA.y = fmaf(ea.y, xa.y, accA.y);
        accA.z = fmaf(ea.z, xa.z, accA.z);
        accA.w = fmaf(ea.w, xa.w, accA.w);
        accB.x = fmaf(eb.x, xb.x, accB.x);
        accB.y = fmaf(eb.y, xb.y, accB.y);
        accB.z = fmaf(eb.z, xb.z, accB.z);
        accB.w = fmaf(eb.w, xb.w, accB.w);
    }
    while (jA < r1A) {
        int sa = __builtin_amdgcn_readfirstlane(sA);
        float4 xa = xb4[(size_t)sa * H_F + lane];
        float4 la = ls4[sa];
        ++jA; if (jA < r1A) sA = csr_src[jA];
        float4 ea = lexp4(la, bldA);
        denA.x += ea.x; denA.y += ea.y; denA.z += ea.z; denA.w += ea.w;
        accA.x = fmaf(ea.x, xa.x, accA.x);
        accA.y = fmaf(ea.y, xa.y, accA.y);
        accA.z = fmaf(ea.z, xa.z, accA.z);
        accA.w = fmaf(ea.w, xa.w, accA.w);
    }
    while (jB < r1B) {
        int sb = __builtin_amdgcn_readfirstlane(sB);
        float4 xb = xb4[(size_t)sb * H_F + lane];
        float4 lb = ls4[sb];
        ++jB; if (jB < r1B) sB = csr_src[jB];
        float4 eb = lexp4(lb, bldB);
        denB.x += eb.x; denB.y += eb.y; denB.z += eb.z; denB.w += eb.w;
        accB.x = fmaf(eb.x, xb.x, accB.x);
        accB.y = fmaf(eb.y, xb.y, accB.y);
        accB.z = fmaf(eb.z, xb.z, accB.z);
        accB.w = fmaf(eb.w, xb.w, accB.w);
    }

    float bv = bias[lane];
    float resA = 0.25f * (accA.x / denA.x + accA.y / denA.y +
                          accA.z / denA.z + accA.w / denA.w);
    float resB = 0.25f * (accB.x / denB.x + accB.y / denB.y +
                          accB.z / denB.z + accB.w / denB.w);
    hout[(size_t)dA * H_F + lane] = fmaxf(resA + bv, 0.f);
    hout[(size_t)dB * H_F + lane] = fmaxf(resB + bv, 0.f);
}

// ---------------- pooling (starts fused in via binary search) ----------------
__global__ void k_pool(const float* __restrict__ h, const int* __restrict__ batch,
                       float* __restrict__ pooledT) {
    int g = blockIdx.x;
    int s, e;
    {
        int lo = 0, hi = NN;
        while (lo < hi) { int mid = (lo + hi) >> 1; if (batch[mid] < g) lo = mid + 1; else hi = mid; }
        s = lo;
        lo = 0; hi = NN;
        int g1 = g + 1;
        while (lo < hi) { int mid = (lo + hi) >> 1; if (batch[mid] < g1) lo = mid + 1; else hi = mid; }
        e = lo;
    }
    int t = threadIdx.x;
    int c = t & 63, j = t >> 6;
    float sum = 0.f;
    for (int n = s + j; n < e; n += 4) sum += h[(size_t)n * H_F + c];
    __shared__ float lds[256];
    lds[t] = sum;
    __syncthreads();
    if (j == 0) {
        float tot = lds[c] + lds[64 + c] + lds[128 + c] + lds[192 + c];
        int cnt = e - s;
        float inv = 1.0f / (float)(cnt > 0 ? cnt : 1);
        pooledT[c * GG + g] = tot * inv;
    }
}

// ---------------- final FC: out[g,o] = sum_c pooledT[c][g]*Wfc[c,o] + bfc[o] --
__global__ __launch_bounds__(256) void k_fc(const float* __restrict__ pooledT,
                                            const float* __restrict__ Wfc,
                                            const float* __restrict__ bfc,
                                            float* __restrict__ out) {
    int o = blockIdx.x * blockDim.x + threadIdx.x;
    if (o >= OUT_F) return;
    float acc[GG];
#pragma unroll
    for (int g = 0; g < GG; ++g) acc[g] = 0.f;
    for (int c = 0; c < H_F; ++c) {
        float w = Wfc[(size_t)c * OUT_F + o];
        const float4* pr4 = (const float4*)(pooledT + c * GG);
#pragma unroll
        for (int g4 = 0; g4 < GG / 4; ++g4) {
            float4 p = pr4[g4];
            acc[4 * g4 + 0] = fmaf(p.x, w, acc[4 * g4 + 0]);
            acc[4 * g4 + 1] = fmaf(p.y, w, acc[4 * g4 + 1]);
            acc[4 * g4 + 2] = fmaf(p.z, w, acc[4 * g4 + 2]);
            acc[4 * g4 + 3] = fmaf(p.w, w, acc[4 * g4 + 3]);
        }
    }
    float bv = bfc[o];
    for (int g = 0; g < GG; ++g) out[(size_t)g * OUT_F + o] = acc[g] + bv;
}

extern "C" void kernel_launch(void* const* d_in, const int* in_sizes, int n_in,
                              void* d_out, int out_size, void* d_ws, size_t ws_size,
                              hipStream_t stream) {
    const float* x      = (const float*)d_in[0];
    const int*   eidx   = (const int*)d_in[1];
    const int*   batch  = (const int*)d_in[3];
    const float* W_emb  = (const float*)d_in[4];
    const float* b_emb  = (const float*)d_in[5];
    const float* W_fc   = (const float*)d_in[6];
    const float* b_fc   = (const float*)d_in[7];
    const float* Wl[3]   = {(const float*)d_in[8],  (const float*)d_in[12], (const float*)d_in[16]};
    const float* asl[3]  = {(const float*)d_in[9],  (const float*)d_in[13], (const float*)d_in[17]};
    const float* adl[3]  = {(const float*)d_in[10], (const float*)d_in[14], (const float*)d_in[18]};
    const float* bl[3]   = {(const float*)d_in[11], (const float*)d_in[15], (const float*)d_in[19]};

    const int* src = eidx;
    const int* dst = eidx + EE;

    // workspace carving (~81.5 MB)
    float* xbuf    = (float*)d_ws;                     // N*256
    float* hA      = xbuf + (size_t)NN * 256;          // N*64
    float* hB      = hA + (size_t)NN * 64;             // N*64
    float* ls      = hB + (size_t)NN * 64;             // N*4
    float* ldb     = ls + (size_t)NN * 4;              // N*4
    float* pooledT = ldb + (size_t)NN * 4;             // 64*64
    int*   cnt     = (int*)(pooledT + GG * GG);        // N
    int*   row     = cnt + NN;                         // N+1 (pad to N+4)
    int*   cursor  = row + NN + 4;                     // N
    int*   csr_src = cursor + NN;                      // E+N

    // ---- CSR build (once; graph identical for all 3 layers) ----
    hipMemsetAsync(cnt, 0, (size_t)NN * sizeof(int), stream);
    k_count<<<(EE + NN + 255) / 256, 256, 0, stream>>>(dst, cnt);
    k_scan_one<<<1, 1024, 0, stream>>>(cnt, row, cursor);
    k_scatter<<<(EE + NN + 255) / 256, 256, 0, stream>>>(src, dst, cursor, csr_src);

    k_emb<<<(NN + 31) / 32, 256, 0, stream>>>(x, W_emb, b_emb, hA);

    float* hcur = hA;
    float* hnext = hB;
    for (int l = 0; l < 3; ++l) {
        k_gemm_layer<<<(NN + 63) / 64, 512, 0, stream>>>(hcur, Wl[l], asl[l], adl[l],
                                                         xbuf, ls, ldb);
        k_aggr_csr<<<NN / 8, 256, 0, stream>>>(row, csr_src,
                                               (const float4*)ls, (const float4*)ldb,
                                               (const float4*)xbuf, bl[l], hnext);
        float* tmp = hcur; hcur = hnext; hnext = tmp;
    }

    k_pool<<<GG, 256, 0, stream>>>(hcur, batch, pooledT);
    k_fc<<<(OUT_F + 255) / 256, 256, 0, stream>>>(pooledT, W_fc, b_fc, (float*)d_out);
}

// Round 8
// 1104.613 us; speedup vs baseline: 1.0263x; 1.0263x over previous
//
#include <hip/hip_runtime.h>

#define NN 50000
#define EE 500000
#define GG 64
#define IN_F 128
#define H_F 64
#define HEADS 4
#define OUT_F 326000
#define NEG 0.2f

// ---------------- embedding GEMM: h0 = x @ W_emb + b_emb ----------------
__global__ __launch_bounds__(256) void k_emb(const float* __restrict__ x,
                                             const float* __restrict__ Wemb,
                                             const float* __restrict__ bemb,
                                             float* __restrict__ h0) {
    __shared__ float wlds[IN_F * H_F];  // [k][c], 32 KB
    int t = threadIdx.x;
#pragma unroll
    for (int i = 0; i < (IN_F * H_F) / (4 * 256); ++i)
        ((float4*)wlds)[t + 256 * i] = ((const float4*)Wemb)[t + 256 * i];
    __syncthreads();

    int c = t & 63, sub = t >> 6;
    int n0 = __builtin_amdgcn_readfirstlane(blockIdx.x * 32 + sub * 8);
    float bv = bemb[c];

    if (n0 + 8 <= NN) {
        const float4* xr = (const float4*)(x + (size_t)n0 * IN_F);
        float acc[8] = {0.f, 0.f, 0.f, 0.f, 0.f, 0.f, 0.f, 0.f};
        for (int k4 = 0; k4 < IN_F / 4; ++k4) {
            float w0 = wlds[(4 * k4 + 0) * H_F + c];
            float w1 = wlds[(4 * k4 + 1) * H_F + c];
            float w2 = wlds[(4 * k4 + 2) * H_F + c];
            float w3 = wlds[(4 * k4 + 3) * H_F + c];
#pragma unroll
            for (int j = 0; j < 8; ++j) {
                float4 xv = xr[j * (IN_F / 4) + k4];
                acc[j] = fmaf(xv.x, w0,
                         fmaf(xv.y, w1,
                         fmaf(xv.z, w2,
                         fmaf(xv.w, w3, acc[j]))));
            }
        }
#pragma unroll
        for (int j = 0; j < 8; ++j)
            h0[(size_t)(n0 + j) * H_F + c] = acc[j] + bv;
    } else {
        for (int j = 0; j < 8; ++j) {
            int n = n0 + j;
            if (n >= NN) break;
            const float* xrow = x + (size_t)n * IN_F;
            float a = 0.f;
            for (int k = 0; k < IN_F; ++k) a += xrow[k] * wlds[k * H_F + c];
            h0[(size_t)n * H_F + c] = a + bv;
        }
    }
}

// ---------------- per-layer GEMM: CHANNEL-split, 32 KB W slice in LDS --------
// blockIdx.x = nb*2 + hp. Block hp owns channels c in [hp*32, hp*32+32) for ALL
// 4 heads: W slice 64k x 128cols = 32 KB -> 5 blocks/CU (the r7 64KB version
// died at ~1 blk/CU). xbuf 16B words (c, h0..h3) stay within one block -> no
// r5-style cross-XCD write amplification. ls/ld become per-hp PARTIALS
// (32-lane reduce); aggr sums the two halves at gather time.
// 256 thr: ci = t&127 -> (head h = ci>>5, local chan cl = ci&31); grp = t>>7
// owns 32 nodes in 8-node batches (acc[8], LDS reads 1:8 vs FMA, h rows as
// wave-uniform float4 broadcasts -> the proven k_emb pattern).
__global__ __launch_bounds__(256) void k_gemm_layer(const float* __restrict__ h,
                                                    const float* __restrict__ W,
                                                    const float* __restrict__ a_src,
                                                    const float* __restrict__ a_dst,
                                                    float* __restrict__ xbuf,
                                                    float* __restrict__ lsp,
                                                    float* __restrict__ ldp) {
    __shared__ float wlds[H_F * 128];   // [k][ci], 32 KB
    int t = threadIdx.x;
    int hp = blockIdx.x & 1;
    int nbase = (blockIdx.x >> 1) * 64;
    {
        // wlds[k][h*32+cl] = W[k][h*64 + hp*32 + cl], float4 over cl
        const float4* W4 = (const float4*)W;   // row stride 64 float4
        float4* wl4 = (float4*)wlds;           // row stride 32 float4
#pragma unroll
        for (int i = 0; i < 8; ++i) {          // 2048 float4 / 256 thr
            int flat = t + 256 * i;
            int k = flat >> 5;
            int rest = flat & 31;              // h*8 + cl4
            int hh = rest >> 3, cl4 = rest & 7;
            wl4[flat] = W4[k * 64 + hh * 16 + hp * 8 + cl4];
        }
    }
    int ci = t & 127, grp = t >> 7;
    int lane = t & 63;
    int hd = ci >> 5, cl = ci & 31;
    float asv = a_src[hd * 64 + hp * 32 + cl];
    float adv = a_dst[hd * 64 + hp * 32 + cl];
    __syncthreads();

    const float* wcol = wlds + ci;             // stride 128 per k
    int base = nbase + grp * 32;
    for (int g = 0; g < 4; ++g) {
        int n0 = __builtin_amdgcn_readfirstlane(base + g * 8);
        if (n0 >= NN) break;                   // NN%8==0 -> groups all-or-nothing
        const float4* hr = (const float4*)(h + (size_t)n0 * H_F);  // wave-uniform
        float acc[8] = {0.f, 0.f, 0.f, 0.f, 0.f, 0.f, 0.f, 0.f};
        for (int k4 = 0; k4 < H_F / 4; ++k4) {
            float w0 = wcol[(4 * k4 + 0) * 128];   // lanes consecutive: no conflict
            float w1 = wcol[(4 * k4 + 1) * 128];
            float w2 = wcol[(4 * k4 + 2) * 128];
            float w3 = wcol[(4 * k4 + 3) * 128];
#pragma unroll
            for (int j = 0; j < 8; ++j) {
                float4 hv = hr[j * (H_F / 4) + k4];  // uniform 16B broadcast
                acc[j] = fmaf(hv.x, w0,
                         fmaf(hv.y, w1,
                         fmaf(hv.z, w2,
                         fmaf(hv.w, w3, acc[j]))));
            }
        }
#pragma unroll
        for (int j = 0; j < 8; ++j) {
            int n = n0 + j;
            // contiguous 512B half-row: [n][c][h], c = hp*32+cl
            xbuf[(size_t)n * (HEADS * H_F) + hp * 128 + cl * 4 + hd] = acc[j];
            float vs = acc[j] * asv, vd = acc[j] * adv;
#pragma unroll
            for (int off = 16; off; off >>= 1) {   // 32-lane (per-head) reduce
                vs += __shfl_xor(vs, off, 64);
                vd += __shfl_xor(vd, off, 64);
            }
            if ((lane & 31) == 0) {
                lsp[((size_t)hp * NN + n) * HEADS + hd] = vs;
                ldp[((size_t)hp * NN + n) * HEADS + hd] = vd;
            }
        }
    }
}

__device__ __forceinline__ float lrelu_exp(float e) {
    e = (e > 0.f) ? e : NEG * e;
    return __expf(e);
}

__device__ __forceinline__ float4 lexp4(float4 s, float4 d) {
    float4 r;
    r.x = lrelu_exp(s.x + d.x);
    r.y = lrelu_exp(s.y + d.y);
    r.z = lrelu_exp(s.z + d.z);
    r.w = lrelu_exp(s.w + d.w);
    return r;
}

__device__ __forceinline__ float4 f4add(float4 a, float4 b) {
    float4 r; r.x = a.x + b.x; r.y = a.y + b.y; r.z = a.z + b.z; r.w = a.w + b.w;
    return r;
}

// ================= CSR build (once per launch; graph static across layers) ====
__global__ void k_count(const int* __restrict__ dst, int* __restrict__ cnt) {
    int i = blockIdx.x * blockDim.x + threadIdx.x;
    if (i >= EE + NN) return;
    int d = (i < EE) ? dst[i] : (i - EE);
    atomicAdd(&cnt[d], 1);
}

#define CHUNK 49          // 1024 * 49 = 50176 >= NN
__global__ __launch_bounds__(1024) void k_scan_one(const int* __restrict__ cnt,
                                                   int* __restrict__ row,
                                                   int* __restrict__ cursor) {
    __shared__ int lds[1024];
    int t = threadIdx.x;
    int c0 = t * CHUNK;
    int c1 = c0 + CHUNK; if (c1 > NN) c1 = NN;
    int s = 0;
    for (int i = c0; i < c1; ++i) s += cnt[i];
    lds[t] = s;
    __syncthreads();
    for (int off = 1; off < 1024; off <<= 1) {
        int add = (t >= off) ? lds[t - off] : 0;
        __syncthreads();
        lds[t] += add;
        __syncthreads();
    }
    int run = (t > 0) ? lds[t - 1] : 0;
    for (int i = c0; i < c1; ++i) {
        row[i] = run;
        cursor[i] = run;
        run += cnt[i];
    }
    if (t == 0) row[NN] = EE + NN;
}

__global__ void k_scatter(const int* __restrict__ src, const int* __restrict__ dst,
                          int* __restrict__ cursor, int* __restrict__ csr_src) {
    int i = blockIdx.x * blockDim.x + threadIdx.x;
    if (i >= EE + NN) return;
    int s, d;
    if (i < EE) { s = src[i]; d = dst[i]; } else { s = d = i - EE; }
    int pos = atomicAdd(&cursor[d], 1);
    csr_src[pos] = s;
}

// ========== fused softmax + aggregation + bias + relu ========================
// ls/ld arrive as two per-hp partials; summed at gather time (tables are
// L2-resident, extra load hidden by MLP).
__global__ __launch_bounds__(256) void k_aggr_csr(const int* __restrict__ row,
                                                  const int* __restrict__ csr_src,
                                                  const float4* __restrict__ lsA,
                                                  const float4* __restrict__ lsB,
                                                  const float4* __restrict__ ldA,
                                                  const float4* __restrict__ ldB,
                                                  const float4* __restrict__ xb4,
                                                  const float* __restrict__ bias,
                                                  float* __restrict__ hout) {
    int t = threadIdx.x;
    int lane = t & 63, wv = t >> 6;
    int dA = blockIdx.x * 8 + wv * 2;       // NN = 50000 = 6250 * 8 exactly
    int dB = dA + 1;
    if (dA >= NN) return;
    int r0A = row[dA], r1A = row[dA + 1];
    int r0B = row[dB], r1B = row[dB + 1];
    float4 bldA = f4add(ldA[dA], ldB[dA]);
    float4 bldB = f4add(ldA[dB], ldB[dB]);
    float4 accA = {0.f, 0.f, 0.f, 0.f}, denA = {1e-16f, 1e-16f, 1e-16f, 1e-16f};
    float4 accB = {0.f, 0.f, 0.f, 0.f}, denB = {1e-16f, 1e-16f, 1e-16f, 1e-16f};

    int jA = r0A, jB = r0B;
    int sA = (jA < r1A) ? csr_src[jA] : 0;
    int sB = (jB < r1B) ? csr_src[jB] : 0;

    while (jA < r1A && jB < r1B) {
        int sa = __builtin_amdgcn_readfirstlane(sA);
        int sb = __builtin_amdgcn_readfirstlane(sB);
        float4 xa = xb4[(size_t)sa * H_F + lane];
        float4 xb = xb4[(size_t)sb * H_F + lane];
        float4 la = f4add(lsA[sa], lsB[sa]);
        float4 lb = f4add(lsA[sb], lsB[sb]);
        ++jA; if (jA < r1A) sA = csr_src[jA];
        ++jB; if (jB < r1B) sB = csr_src[jB];
        float4 ea = lexp4(la, bldA);
        float4 eb = lexp4(lb, bldB);
        denA.x += ea.x; denA.y += ea.y; denA.z += ea.z; denA.w += ea.w;
        denB.x += eb.x; denB.y += eb.y; denB.z += eb.z; denB.w += eb.w;
        accA.x = fmaf(ea.x, xa.x, accA.x);
        accA.y = fmaf(ea.y, xa.y, accA.y);
        accA.z = fmaf(ea.z, xa.z, accA.z);
        accA.w = fmaf(ea.w, xa.w, accA.w);
        accB.x = fmaf(eb.x, xb.x, accB.x);
        accB.y = fmaf(eb.y, xb.y, accB.y);
        accB.z = fmaf(eb.z, xb.z, accB.z);
        accB.w = fmaf(eb.w, xb.w, accB.w);
    }
    while (jA < r1A) {
        int sa = __builtin_amdgcn_readfirstlane(sA);
        float4 xa = xb4[(size_t)sa * H_F + lane];
        float4 la = f4add(lsA[sa], lsB[sa]);
        ++jA; if (jA < r1A) sA = csr_src[jA];
        float4 ea = lexp4(la, bldA);
        denA.x += ea.x; denA.y += ea.y; denA.z += ea.z; denA.w += ea.w;
        accA.x = fmaf(ea.x, xa.x, accA.x);
        accA.y = fmaf(ea.y, xa.y, accA.y);
        accA.z = fmaf(ea.z, xa.z, accA.z);
        accA.w = fmaf(ea.w, xa.w, accA.w);
    }
    while (jB < r1B) {
        int sb = __builtin_amdgcn_readfirstlane(sB);
        float4 xb = xb4[(size_t)sb * H_F + lane];
        float4 lb = f4add(lsA[sb], lsB[sb]);
        ++jB; if (jB < r1B) sB = csr_src[jB];
        float4 eb = lexp4(lb, bldB);
        denB.x += eb.x; denB.y += eb.y; denB.z += eb.z; denB.w += eb.w;
        accB.x = fmaf(eb.x, xb.x, accB.x);
        accB.y = fmaf(eb.y, xb.y, accB.y);
        accB.z = fmaf(eb.z, xb.z, accB.z);
        accB.w = fmaf(eb.w, xb.w, accB.w);
    }

    float bv = bias[lane];
    float resA = 0.25f * (accA.x / denA.x + accA.y / denA.y +
                          accA.z / denA.z + accA.w / denA.w);
    float resB = 0.25f * (accB.x / denB.x + accB.y / denB.y +
                          accB.z / denB.z + accB.w / denB.w);
    hout[(size_t)dA * H_F + lane] = fmaxf(resA + bv, 0.f);
    hout[(size_t)dB * H_F + lane] = fmaxf(resB + bv, 0.f);
}

// ---------------- pooling (starts fused in via binary search) ----------------
__global__ void k_pool(const float* __restrict__ h, const int* __restrict__ batch,
                       float* __restrict__ pooledT) {
    int g = blockIdx.x;
    int s, e;
    {
        int lo = 0, hi = NN;
        while (lo < hi) { int mid = (lo + hi) >> 1; if (batch[mid] < g) lo = mid + 1; else hi = mid; }
        s = lo;
        lo = 0; hi = NN;
        int g1 = g + 1;
        while (lo < hi) { int mid = (lo + hi) >> 1; if (batch[mid] < g1) lo = mid + 1; else hi = mid; }
        e = lo;
    }
    int t = threadIdx.x;
    int c = t & 63, j = t >> 6;
    float sum = 0.f;
    for (int n = s + j; n < e; n += 4) sum += h[(size_t)n * H_F + c];
    __shared__ float lds[256];
    lds[t] = sum;
    __syncthreads();
    if (j == 0) {
        float tot = lds[c] + lds[64 + c] + lds[128 + c] + lds[192 + c];
        int cnt = e - s;
        float inv = 1.0f / (float)(cnt > 0 ? cnt : 1);
        pooledT[c * GG + g] = tot * inv;
    }
}

// ---------------- final FC: out[g,o] = sum_c pooledT[c][g]*Wfc[c,o] + bfc[o] --
__global__ __launch_bounds__(256) void k_fc(const float* __restrict__ pooledT,
                                            const float* __restrict__ Wfc,
                                            const float* __restrict__ bfc,
                                            float* __restrict__ out) {
    int o = blockIdx.x * blockDim.x + threadIdx.x;
    if (o >= OUT_F) return;
    float acc[GG];
#pragma unroll
    for (int g = 0; g < GG; ++g) acc[g] = 0.f;
    for (int c = 0; c < H_F; ++c) {
        float w = Wfc[(size_t)c * OUT_F + o];
        const float4* pr4 = (const float4*)(pooledT + c * GG);
#pragma unroll
        for (int g4 = 0; g4 < GG / 4; ++g4) {
            float4 p = pr4[g4];
            acc[4 * g4 + 0] = fmaf(p.x, w, acc[4 * g4 + 0]);
            acc[4 * g4 + 1] = fmaf(p.y, w, acc[4 * g4 + 1]);
            acc[4 * g4 + 2] = fmaf(p.z, w, acc[4 * g4 + 2]);
            acc[4 * g4 + 3] = fmaf(p.w, w, acc[4 * g4 + 3]);
        }
    }
    float bv = bfc[o];
    for (int g = 0; g < GG; ++g) out[(size_t)g * OUT_F + o] = acc[g] + bv;
}

extern "C" void kernel_launch(void* const* d_in, const int* in_sizes, int n_in,
                              void* d_out, int out_size, void* d_ws, size_t ws_size,
                              hipStream_t stream) {
    const float* x      = (const float*)d_in[0];
    const int*   eidx   = (const int*)d_in[1];
    const int*   batch  = (const int*)d_in[3];
    const float* W_emb  = (const float*)d_in[4];
    const float* b_emb  = (const float*)d_in[5];
    const float* W_fc   = (const float*)d_in[6];
    const float* b_fc   = (const float*)d_in[7];
    const float* Wl[3]   = {(const float*)d_in[8],  (const float*)d_in[12], (const float*)d_in[16]};
    const float* asl[3]  = {(const float*)d_in[9],  (const float*)d_in[13], (const float*)d_in[17]};
    const float* adl[3]  = {(const float*)d_in[10], (const float*)d_in[14], (const float*)d_in[18]};
    const float* bl[3]   = {(const float*)d_in[11], (const float*)d_in[15], (const float*)d_in[19]};

    const int* src = eidx;
    const int* dst = eidx + EE;

    // workspace carving (~83 MB)
    float* xbuf    = (float*)d_ws;                     // N*256
    float* hA      = xbuf + (size_t)NN * 256;          // N*64
    float* hB      = hA + (size_t)NN * 64;             // N*64
    float* lsp     = hB + (size_t)NN * 64;             // 2*N*4 (hp partials)
    float* ldp     = lsp + (size_t)2 * NN * 4;         // 2*N*4
    float* pooledT = ldp + (size_t)2 * NN * 4;         // 64*64
    int*   cnt     = (int*)(pooledT + GG * GG);        // N
    int*   row     = cnt + NN;                         // N+1 (pad to N+4)
    int*   cursor  = row + NN + 4;                     // N
    int*   csr_src = cursor + NN;                      // E+N

    // ---- CSR build (once; graph identical for all 3 layers) ----
    hipMemsetAsync(cnt, 0, (size_t)NN * sizeof(int), stream);
    k_count<<<(EE + NN + 255) / 256, 256, 0, stream>>>(dst, cnt);
    k_scan_one<<<1, 1024, 0, stream>>>(cnt, row, cursor);
    k_scatter<<<(EE + NN + 255) / 256, 256, 0, stream>>>(src, dst, cursor, csr_src);

    k_emb<<<(NN + 31) / 32, 256, 0, stream>>>(x, W_emb, b_emb, hA);

    float* hcur = hA;
    float* hnext = hB;
    for (int l = 0; l < 3; ++l) {
        k_gemm_layer<<<2 * ((NN + 63) / 64), 256, 0, stream>>>(hcur, Wl[l], asl[l], adl[l],
                                                               xbuf, lsp, ldp);
        k_aggr_csr<<<NN / 8, 256, 0, stream>>>(row, csr_src,
                                               (const float4*)lsp,
                                               (const float4*)(lsp + (size_t)NN * 4),
                                               (const float4*)ldp,
                                               (const float4*)(ldp + (size_t)NN * 4),
                                               (const float4*)xbuf, bl[l], hnext);
        float* tmp = hcur; hcur = hnext; hnext = tmp;
    }

    k_pool<<<GG, 256, 0, stream>>>(hcur, batch, pooledT);
    k_fc<<<(OUT_F + 255) / 256, 256, 0, stream>>>(pooledT, W_fc, b_fc, (float*)d_out);
}

// Round 9
// 945.339 us; speedup vs baseline: 1.1992x; 1.1685x over previous
//
#include <hip/hip_runtime.h>

#define NN 50000
#define EE 500000
#define GG 64
#define IN_F 128
#define H_F 64
#define HEADS 4
#define OUT_F 326000
#define NEG 0.2f

// ---------------- embedding GEMM: h0 = x @ W_emb + b_emb ----------------
__global__ __launch_bounds__(256) void k_emb(const float* __restrict__ x,
                                             const float* __restrict__ Wemb,
                                             const float* __restrict__ bemb,
                                             float* __restrict__ h0) {
    __shared__ float wlds[IN_F * H_F];  // [k][c], 32 KB
    int t = threadIdx.x;
#pragma unroll
    for (int i = 0; i < (IN_F * H_F) / (4 * 256); ++i)
        ((float4*)wlds)[t + 256 * i] = ((const float4*)Wemb)[t + 256 * i];
    __syncthreads();

    int c = t & 63, sub = t >> 6;
    int n0 = __builtin_amdgcn_readfirstlane(blockIdx.x * 32 + sub * 8);
    float bv = bemb[c];

    if (n0 + 8 <= NN) {
        const float4* xr = (const float4*)(x + (size_t)n0 * IN_F);
        float acc[8] = {0.f, 0.f, 0.f, 0.f, 0.f, 0.f, 0.f, 0.f};
        for (int k4 = 0; k4 < IN_F / 4; ++k4) {
            float w0 = wlds[(4 * k4 + 0) * H_F + c];
            float w1 = wlds[(4 * k4 + 1) * H_F + c];
            float w2 = wlds[(4 * k4 + 2) * H_F + c];
            float w3 = wlds[(4 * k4 + 3) * H_F + c];
#pragma unroll
            for (int j = 0; j < 8; ++j) {
                float4 xv = xr[j * (IN_F / 4) + k4];
                acc[j] = fmaf(xv.x, w0,
                         fmaf(xv.y, w1,
                         fmaf(xv.z, w2,
                         fmaf(xv.w, w3, acc[j]))));
            }
        }
#pragma unroll
        for (int j = 0; j < 8; ++j)
            h0[(size_t)(n0 + j) * H_F + c] = acc[j] + bv;
    } else {
        for (int j = 0; j < 8; ++j) {
            int n = n0 + j;
            if (n >= NN) break;
            const float* xrow = x + (size_t)n * IN_F;
            float a = 0.f;
            for (int k = 0; k < IN_F; ++k) a += xrow[k] * wlds[k * H_F + c];
            h0[(size_t)n * H_F + c] = a + bv;
        }
    }
}

// ---------------- per-layer GEMM: EXACT r2 register-weight body --------------
// The only change vs the proven <85 µs r2 version: store index t -> lane*4+wv
// (directly writes the transposed xbuf[n][c][h] the aggr gather wants; r3/r4
// showed the strided store is cost-neutral). Everything else byte-identical:
// scalar wave-uniform h broadcasts, single FMA chain, one node/iter, no
// launch_bounds -> allocator historically picks ~88 VGPR and keeps wreg[64].
__global__ void k_gemm_layer(const float* __restrict__ h, const float* __restrict__ W,
                             const float* __restrict__ a_src, const float* __restrict__ a_dst,
                             float* __restrict__ xbuf, float* __restrict__ ls,
                             float* __restrict__ ld) {
    int t = threadIdx.x;
    int lane = t & 63, wv = t >> 6;
    float wreg[H_F];
#pragma unroll
    for (int k = 0; k < H_F; ++k) wreg[k] = W[k * (HEADS * H_F) + t];
    float asv = a_src[t], adv = a_dst[t];
    int base = blockIdx.x * 32;
    for (int i = 0; i < 32; ++i) {
        int n = base + i;
        if (n >= NN) return;
        const float* hr = h + (size_t)n * H_F;
        float acc = 0.f;
#pragma unroll
        for (int k = 0; k < H_F; ++k) acc += hr[k] * wreg[k];
        xbuf[(size_t)n * (HEADS * H_F) + lane * 4 + wv] = acc;   // [n][c][h]
        float vs = acc * asv, vd = acc * adv;
#pragma unroll
        for (int off = 32; off; off >>= 1) {
            vs += __shfl_xor(vs, off, 64);
            vd += __shfl_xor(vd, off, 64);
        }
        if (lane == 0) {
            ls[n * HEADS + wv] = vs;
            ld[n * HEADS + wv] = vd;
        }
    }
}

__device__ __forceinline__ float lrelu_exp(float e) {
    e = (e > 0.f) ? e : NEG * e;
    return __expf(e);
}

__device__ __forceinline__ float4 lexp4(float4 s, float4 d) {
    float4 r;
    r.x = lrelu_exp(s.x + d.x);
    r.y = lrelu_exp(s.y + d.y);
    r.z = lrelu_exp(s.z + d.z);
    r.w = lrelu_exp(s.w + d.w);
    return r;
}

// ================= CSR build (once per launch; graph static across layers) ====
__global__ void k_count(const int* __restrict__ dst, int* __restrict__ cnt) {
    int i = blockIdx.x * blockDim.x + threadIdx.x;
    if (i >= EE + NN) return;
    int d = (i < EE) ? dst[i] : (i - EE);
    atomicAdd(&cnt[d], 1);
}

#define CHUNK 49          // 1024 * 49 = 50176 >= NN
__global__ __launch_bounds__(1024) void k_scan_one(const int* __restrict__ cnt,
                                                   int* __restrict__ row,
                                                   int* __restrict__ cursor) {
    __shared__ int lds[1024];
    int t = threadIdx.x;
    int c0 = t * CHUNK;
    int c1 = c0 + CHUNK; if (c1 > NN) c1 = NN;
    int s = 0;
    for (int i = c0; i < c1; ++i) s += cnt[i];
    lds[t] = s;
    __syncthreads();
    for (int off = 1; off < 1024; off <<= 1) {
        int add = (t >= off) ? lds[t - off] : 0;
        __syncthreads();
        lds[t] += add;
        __syncthreads();
    }
    int run = (t > 0) ? lds[t - 1] : 0;
    for (int i = c0; i < c1; ++i) {
        row[i] = run;
        cursor[i] = run;
        run += cnt[i];
    }
    if (t == 0) row[NN] = EE + NN;
}

__global__ void k_scatter(const int* __restrict__ src, const int* __restrict__ dst,
                          int* __restrict__ cursor, int* __restrict__ csr_src) {
    int i = blockIdx.x * blockDim.x + threadIdx.x;
    if (i >= EE + NN) return;
    int s, d;
    if (i < EE) { s = src[i]; d = dst[i]; } else { s = d = i - EE; }
    int pos = atomicAdd(&cursor[d], 1);
    csr_src[pos] = s;
}

// ========== fused softmax + aggregation + bias + relu ========================
// One wave per TWO nodes (interleaved edge streams for MLP), csr prefetch 1
// ahead, xbuf in [node][chan][head] layout -> one dwordx4 per lane per edge.
__global__ __launch_bounds__(256) void k_aggr_csr(const int* __restrict__ row,
                                                  const int* __restrict__ csr_src,
                                                  const float4* __restrict__ ls4,
                                                  const float4* __restrict__ ld4,
                                                  const float4* __restrict__ xb4,
                                                  const float* __restrict__ bias,
                                                  float* __restrict__ hout) {
    int t = threadIdx.x;
    int lane = t & 63, wv = t >> 6;
    int dA = blockIdx.x * 8 + wv * 2;       // NN = 50000 = 6250 * 8 exactly
    int dB = dA + 1;
    if (dA >= NN) return;
    int r0A = row[dA], r1A = row[dA + 1];
    int r0B = row[dB], r1B = row[dB + 1];
    float4 bldA = ld4[dA];
    float4 bldB = ld4[dB];
    float4 accA = {0.f, 0.f, 0.f, 0.f}, denA = {1e-16f, 1e-16f, 1e-16f, 1e-16f};
    float4 accB = {0.f, 0.f, 0.f, 0.f}, denB = {1e-16f, 1e-16f, 1e-16f, 1e-16f};

    int jA = r0A, jB = r0B;
    int sA = (jA < r1A) ? csr_src[jA] : 0;
    int sB = (jB < r1B) ? csr_src[jB] : 0;

    while (jA < r1A && jB < r1B) {
        int sa = __builtin_amdgcn_readfirstlane(sA);
        int sb = __builtin_amdgcn_readfirstlane(sB);
        float4 xa = xb4[(size_t)sa * H_F + lane];
        float4 xb = xb4[(size_t)sb * H_F + lane];
        float4 la = ls4[sa];
        float4 lb = ls4[sb];
        ++jA; if (jA < r1A) sA = csr_src[jA];
        ++jB; if (jB < r1B) sB = csr_src[jB];
        float4 ea = lexp4(la, bldA);
        float4 eb = lexp4(lb, bldB);
        denA.x += ea.x; denA.y += ea.y; denA.z += ea.z; denA.w += ea.w;
        denB.x += eb.x; denB.y += eb.y; denB.z += eb.z; denB.w += eb.w;
        accA.x = fmaf(ea.x, xa.x, accA.x);
        accA.y = fmaf(ea.y, xa.y, accA.y);
        accA.z = fmaf(ea.z, xa.z, accA.z);
        accA.w = fmaf(ea.w, xa.w, accA.w);
        accB.x = fmaf(eb.x, xb.x, accB.x);
        accB.y = fmaf(eb.y, xb.y, accB.y);
        accB.z = fmaf(eb.z, xb.z, accB.z);
        accB.w = fmaf(eb.w, xb.w, accB.w);
    }
    while (jA < r1A) {
        int sa = __builtin_amdgcn_readfirstlane(sA);
        float4 xa = xb4[(size_t)sa * H_F + lane];
        float4 la = ls4[sa];
        ++jA; if (jA < r1A) sA = csr_src[jA];
        float4 ea = lexp4(la, bldA);
        denA.x += ea.x; denA.y += ea.y; denA.z += ea.z; denA.w += ea.w;
        accA.x = fmaf(ea.x, xa.x, accA.x);
        accA.y = fmaf(ea.y, xa.y, accA.y);
        accA.z = fmaf(ea.z, xa.z, accA.z);
        accA.w = fmaf(ea.w, xa.w, accA.w);
    }
    while (jB < r1B) {
        int sb = __builtin_amdgcn_readfirstlane(sB);
        float4 xb = xb4[(size_t)sb * H_F + lane];
        float4 lb = ls4[sb];
        ++jB; if (jB < r1B) sB = csr_src[jB];
        float4 eb = lexp4(lb, bldB);
        denB.x += eb.x; denB.y += eb.y; denB.z += eb.z; denB.w += eb.w;
        accB.x = fmaf(eb.x, xb.x, accB.x);
        accB.y = fmaf(eb.y, xb.y, accB.y);
        accB.z = fmaf(eb.z, xb.z, accB.z);
        accB.w = fmaf(eb.w, xb.w, accB.w);
    }

    float bv = bias[lane];
    float resA = 0.25f * (accA.x / denA.x + accA.y / denA.y +
                          accA.z / denA.z + accA.w / denA.w);
    float resB = 0.25f * (accB.x / denB.x + accB.y / denB.y +
                          accB.z / denB.z + accB.w / denB.w);
    hout[(size_t)dA * H_F + lane] = fmaxf(resA + bv, 0.f);
    hout[(size_t)dB * H_F + lane] = fmaxf(resB + bv, 0.f);
}

// ---------------- pooling (starts fused in via binary search) ----------------
__global__ void k_pool(const float* __restrict__ h, const int* __restrict__ batch,
                       float* __restrict__ pooledT) {
    int g = blockIdx.x;
    int s, e;
    {
        int lo = 0, hi = NN;
        while (lo < hi) { int mid = (lo + hi) >> 1; if (batch[mid] < g) lo = mid + 1; else hi = mid; }
        s = lo;
        lo = 0; hi = NN;
        int g1 = g + 1;
        while (lo < hi) { int mid = (lo + hi) >> 1; if (batch[mid] < g1) lo = mid + 1; else hi = mid; }
        e = lo;
    }
    int t = threadIdx.x;
    int c = t & 63, j = t >> 6;
    float sum = 0.f;
    for (int n = s + j; n < e; n += 4) sum += h[(size_t)n * H_F + c];
    __shared__ float lds[256];
    lds[t] = sum;
    __syncthreads();
    if (j == 0) {
        float tot = lds[c] + lds[64 + c] + lds[128 + c] + lds[192 + c];
        int cnt = e - s;
        float inv = 1.0f / (float)(cnt > 0 ? cnt : 1);
        pooledT[c * GG + g] = tot * inv;
    }
}

// ---------------- final FC: out[g,o] = sum_c pooledT[c][g]*Wfc[c,o] + bfc[o] --
// pooledT staged in LDS (16 KB): inner loop reads LDS broadcasts instead of
// 1024 L1 VMEM ops per thread.
__global__ __launch_bounds__(256) void k_fc(const float* __restrict__ pooledT,
                                            const float* __restrict__ Wfc,
                                            const float* __restrict__ bfc,
                                            float* __restrict__ out) {
    __shared__ float plds[GG * GG];   // [c][g], 16 KB
    int t = threadIdx.x;
#pragma unroll
    for (int i = 0; i < (GG * GG) / (4 * 256); ++i)   // 4 float4/thread
        ((float4*)plds)[t + 256 * i] = ((const float4*)pooledT)[t + 256 * i];
    __syncthreads();

    int o = blockIdx.x * blockDim.x + t;
    if (o >= OUT_F) return;
    float acc[GG];
#pragma unroll
    for (int g = 0; g < GG; ++g) acc[g] = 0.f;
    for (int c = 0; c < H_F; ++c) {
        float w = Wfc[(size_t)c * OUT_F + o];
        const float4* pr4 = (const float4*)(plds + c * GG);
#pragma unroll
        for (int g4 = 0; g4 < GG / 4; ++g4) {
            float4 p = pr4[g4];
            acc[4 * g4 + 0] = fmaf(p.x, w, acc[4 * g4 + 0]);
            acc[4 * g4 + 1] = fmaf(p.y, w, acc[4 * g4 + 1]);
            acc[4 * g4 + 2] = fmaf(p.z, w, acc[4 * g4 + 2]);
            acc[4 * g4 + 3] = fmaf(p.w, w, acc[4 * g4 + 3]);
        }
    }
    float bv = bfc[o];
    for (int g = 0; g < GG; ++g) out[(size_t)g * OUT_F + o] = acc[g] + bv;
}

extern "C" void kernel_launch(void* const* d_in, const int* in_sizes, int n_in,
                              void* d_out, int out_size, void* d_ws, size_t ws_size,
                              hipStream_t stream) {
    const float* x      = (const float*)d_in[0];
    const int*   eidx   = (const int*)d_in[1];
    const int*   batch  = (const int*)d_in[3];
    const float* W_emb  = (const float*)d_in[4];
    const float* b_emb  = (const float*)d_in[5];
    const float* W_fc   = (const float*)d_in[6];
    const float* b_fc   = (const float*)d_in[7];
    const float* Wl[3]   = {(const float*)d_in[8],  (const float*)d_in[12], (const float*)d_in[16]};
    const float* asl[3]  = {(const float*)d_in[9],  (const float*)d_in[13], (const float*)d_in[17]};
    const float* adl[3]  = {(const float*)d_in[10], (const float*)d_in[14], (const float*)d_in[18]};
    const float* bl[3]   = {(const float*)d_in[11], (const float*)d_in[15], (const float*)d_in[19]};

    const int* src = eidx;
    const int* dst = eidx + EE;

    // workspace carving (~81.5 MB)
    float* xbuf    = (float*)d_ws;                     // N*256
    float* hA      = xbuf + (size_t)NN * 256;          // N*64
    float* hB      = hA + (size_t)NN * 64;             // N*64
    float* ls      = hB + (size_t)NN * 64;             // N*4
    float* ldb     = ls + (size_t)NN * 4;              // N*4
    float* pooledT = ldb + (size_t)NN * 4;             // 64*64
    int*   cnt     = (int*)(pooledT + GG * GG);        // N
    int*   row     = cnt + NN;                         // N+1 (pad to N+4)
    int*   cursor  = row + NN + 4;                     // N
    int*   csr_src = cursor + NN;                      // E+N

    // ---- CSR build (once; graph identical for all 3 layers) ----
    hipMemsetAsync(cnt, 0, (size_t)NN * sizeof(int), stream);
    k_count<<<(EE + NN + 255) / 256, 256, 0, stream>>>(dst, cnt);
    k_scan_one<<<1, 1024, 0, stream>>>(cnt, row, cursor);
    k_scatter<<<(EE + NN + 255) / 256, 256, 0, stream>>>(src, dst, cursor, csr_src);

    k_emb<<<(NN + 31) / 32, 256, 0, stream>>>(x, W_emb, b_emb, hA);

    float* hcur = hA;
    float* hnext = hB;
    for (int l = 0; l < 3; ++l) {
        k_gemm_layer<<<(NN + 31) / 32, 256, 0, stream>>>(hcur, Wl[l], asl[l], adl[l],
                                                         xbuf, ls, ldb);
        k_aggr_csr<<<NN / 8, 256, 0, stream>>>(row, csr_src,
                                               (const float4*)ls, (const float4*)ldb,
                                               (const float4*)xbuf, bl[l], hnext);
        float* tmp = hcur; hcur = hnext; hnext = tmp;
    }

    k_pool<<<GG, 256, 0, stream>>>(hcur, batch, pooledT);
    k_fc<<<(OUT_F + 255) / 256, 256, 0, stream>>>(pooledT, W_fc, b_fc, (float*)d_out);
}

// Round 10
// 850.137 us; speedup vs baseline: 1.3334x; 1.1120x over previous
//
#include <hip/hip_runtime.h>

#define NN 50000
#define EE 500000
#define GG 64
#define IN_F 128
#define H_F 64
#define HEADS 4
#define OUT_F 326000
#define NEG 0.2f
#define SCAN_B 256
#define NBLK ((NN + SCAN_B - 1) / SCAN_B)   // 196

// ---------------- embedding GEMM: h0 = x @ W_emb + b_emb ----------------
__global__ __launch_bounds__(256) void k_emb(const float* __restrict__ x,
                                             const float* __restrict__ Wemb,
                                             const float* __restrict__ bemb,
                                             float* __restrict__ h0) {
    __shared__ float wlds[IN_F * H_F];  // [k][c], 32 KB
    int t = threadIdx.x;
#pragma unroll
    for (int i = 0; i < (IN_F * H_F) / (4 * 256); ++i)
        ((float4*)wlds)[t + 256 * i] = ((const float4*)Wemb)[t + 256 * i];
    __syncthreads();

    int c = t & 63, sub = t >> 6;
    int n0 = __builtin_amdgcn_readfirstlane(blockIdx.x * 32 + sub * 8);
    float bv = bemb[c];

    if (n0 + 8 <= NN) {
        const float4* xr = (const float4*)(x + (size_t)n0 * IN_F);
        float acc[8] = {0.f, 0.f, 0.f, 0.f, 0.f, 0.f, 0.f, 0.f};
        for (int k4 = 0; k4 < IN_F / 4; ++k4) {
            float w0 = wlds[(4 * k4 + 0) * H_F + c];
            float w1 = wlds[(4 * k4 + 1) * H_F + c];
            float w2 = wlds[(4 * k4 + 2) * H_F + c];
            float w3 = wlds[(4 * k4 + 3) * H_F + c];
#pragma unroll
            for (int j = 0; j < 8; ++j) {
                float4 xv = xr[j * (IN_F / 4) + k4];
                acc[j] = fmaf(xv.x, w0,
                         fmaf(xv.y, w1,
                         fmaf(xv.z, w2,
                         fmaf(xv.w, w3, acc[j]))));
            }
        }
#pragma unroll
        for (int j = 0; j < 8; ++j)
            h0[(size_t)(n0 + j) * H_F + c] = acc[j] + bv;
    } else {
        for (int j = 0; j < 8; ++j) {
            int n = n0 + j;
            if (n >= NN) break;
            const float* xrow = x + (size_t)n * IN_F;
            float a = 0.f;
            for (int k = 0; k < IN_F; ++k) a += xrow[k] * wlds[k * H_F + c];
            h0[(size_t)n * H_F + c] = a + bv;
        }
    }
}

// ---------------- per-layer GEMM: EXACT r2 register-weight body --------------
// (proven fast in r9: wreg[64] kept resident, transposed [n][c][h] store)
__global__ void k_gemm_layer(const float* __restrict__ h, const float* __restrict__ W,
                             const float* __restrict__ a_src, const float* __restrict__ a_dst,
                             float* __restrict__ xbuf, float* __restrict__ ls,
                             float* __restrict__ ld) {
    int t = threadIdx.x;
    int lane = t & 63, wv = t >> 6;
    float wreg[H_F];
#pragma unroll
    for (int k = 0; k < H_F; ++k) wreg[k] = W[k * (HEADS * H_F) + t];
    float asv = a_src[t], adv = a_dst[t];
    int base = blockIdx.x * 32;
    for (int i = 0; i < 32; ++i) {
        int n = base + i;
        if (n >= NN) return;
        const float* hr = h + (size_t)n * H_F;
        float acc = 0.f;
#pragma unroll
        for (int k = 0; k < H_F; ++k) acc += hr[k] * wreg[k];
        xbuf[(size_t)n * (HEADS * H_F) + lane * 4 + wv] = acc;   // [n][c][h]
        float vs = acc * asv, vd = acc * adv;
#pragma unroll
        for (int off = 32; off; off >>= 1) {
            vs += __shfl_xor(vs, off, 64);
            vd += __shfl_xor(vd, off, 64);
        }
        if (lane == 0) {
            ls[n * HEADS + wv] = vs;
            ld[n * HEADS + wv] = vd;
        }
    }
}

__device__ __forceinline__ float lrelu_exp(float e) {
    e = (e > 0.f) ? e : NEG * e;
    return __expf(e);
}

__device__ __forceinline__ float4 lexp4(float4 s, float4 d) {
    float4 r;
    r.x = lrelu_exp(s.x + d.x);
    r.y = lrelu_exp(s.y + d.y);
    r.z = lrelu_exp(s.z + d.z);
    r.w = lrelu_exp(s.w + d.w);
    return r;
}

// ================= CSR build (once per launch; graph static across layers) ====
// r2's parallel 3-kernel scan chain restored: the r7 single-block k_scan_one
// "dispatch saving" cost 111 µs of serial latency on one CU (r9 top-1).
__global__ void k_count(const int* __restrict__ dst, int* __restrict__ cnt) {
    int i = blockIdx.x * blockDim.x + threadIdx.x;
    if (i >= EE + NN) return;
    int d = (i < EE) ? dst[i] : (i - EE);
    atomicAdd(&cnt[d], 1);
}

__global__ void k_scan1(const int* __restrict__ cnt, int* __restrict__ excl,
                        int* __restrict__ bsum) {
    __shared__ int lds[SCAN_B];
    int t = threadIdx.x, i = blockIdx.x * SCAN_B + t;
    int v = (i < NN) ? cnt[i] : 0;
    lds[t] = v;
    __syncthreads();
    for (int off = 1; off < SCAN_B; off <<= 1) {
        int add = (t >= off) ? lds[t - off] : 0;
        __syncthreads();
        lds[t] += add;
        __syncthreads();
    }
    if (i < NN) excl[i] = lds[t] - v;
    if (t == SCAN_B - 1) bsum[blockIdx.x] = lds[t];
}

__global__ void k_scan2(int* __restrict__ bsum) {
    __shared__ int lds[SCAN_B];
    int t = threadIdx.x;
    int v = (t < NBLK) ? bsum[t] : 0;
    lds[t] = v;
    __syncthreads();
    for (int off = 1; off < SCAN_B; off <<= 1) {
        int add = (t >= off) ? lds[t - off] : 0;
        __syncthreads();
        lds[t] += add;
        __syncthreads();
    }
    if (t < NBLK) bsum[t] = lds[t] - v;
}

__global__ void k_scan3(const int* __restrict__ excl, const int* __restrict__ bsum,
                        int* __restrict__ row, int* __restrict__ cursor) {
    int i = blockIdx.x * blockDim.x + threadIdx.x;
    if (i >= NN) return;
    int r = excl[i] + bsum[i / SCAN_B];
    row[i] = r;
    cursor[i] = r;
    if (i == 0) row[NN] = EE + NN;
}

__global__ void k_scatter(const int* __restrict__ src, const int* __restrict__ dst,
                          int* __restrict__ cursor, int* __restrict__ csr_src) {
    int i = blockIdx.x * blockDim.x + threadIdx.x;
    if (i >= EE + NN) return;
    int s, d;
    if (i < EE) { s = src[i]; d = dst[i]; } else { s = d = i - EE; }
    int pos = atomicAdd(&cursor[d], 1);
    csr_src[pos] = s;
}

// ========== fused softmax + aggregation + bias + relu ========================
// One wave per TWO nodes (interleaved edge streams for MLP), csr prefetch 1
// ahead, xbuf in [node][chan][head] layout -> one dwordx4 per lane per edge.
__global__ __launch_bounds__(256) void k_aggr_csr(const int* __restrict__ row,
                                                  const int* __restrict__ csr_src,
                                                  const float4* __restrict__ ls4,
                                                  const float4* __restrict__ ld4,
                                                  const float4* __restrict__ xb4,
                                                  const float* __restrict__ bias,
                                                  float* __restrict__ hout) {
    int t = threadIdx.x;
    int lane = t & 63, wv = t >> 6;
    int dA = blockIdx.x * 8 + wv * 2;       // NN = 50000 = 6250 * 8 exactly
    int dB = dA + 1;
    if (dA >= NN) return;
    int r0A = row[dA], r1A = row[dA + 1];
    int r0B = row[dB], r1B = row[dB + 1];
    float4 bldA = ld4[dA];
    float4 bldB = ld4[dB];
    float4 accA = {0.f, 0.f, 0.f, 0.f}, denA = {1e-16f, 1e-16f, 1e-16f, 1e-16f};
    float4 accB = {0.f, 0.f, 0.f, 0.f}, denB = {1e-16f, 1e-16f, 1e-16f, 1e-16f};

    int jA = r0A, jB = r0B;
    int sA = (jA < r1A) ? csr_src[jA] : 0;
    int sB = (jB < r1B) ? csr_src[jB] : 0;

    while (jA < r1A && jB < r1B) {
        int sa = __builtin_amdgcn_readfirstlane(sA);
        int sb = __builtin_amdgcn_readfirstlane(sB);
        float4 xa = xb4[(size_t)sa * H_F + lane];
        float4 xb = xb4[(size_t)sb * H_F + lane];
        float4 la = ls4[sa];
        float4 lb = ls4[sb];
        ++jA; if (jA < r1A) sA = csr_src[jA];
        ++jB; if (jB < r1B) sB = csr_src[jB];
        float4 ea = lexp4(la, bldA);
        float4 eb = lexp4(lb, bldB);
        denA.x += ea.x; denA.y += ea.y; denA.z += ea.z; denA.w += ea.w;
        denB.x += eb.x; denB.y += eb.y; denB.z += eb.z; denB.w += eb.w;
        accA.x = fmaf(ea.x, xa.x, accA.x);
        accA.y = fmaf(ea.y, xa.y, accA.y);
        accA.z = fmaf(ea.z, xa.z, accA.z);
        accA.w = fmaf(ea.w, xa.w, accA.w);
        accB.x = fmaf(eb.x, xb.x, accB.x);
        accB.y = fmaf(eb.y, xb.y, accB.y);
        accB.z = fmaf(eb.z, xb.z, accB.z);
        accB.w = fmaf(eb.w, xb.w, accB.w);
    }
    while (jA < r1A) {
        int sa = __builtin_amdgcn_readfirstlane(sA);
        float4 xa = xb4[(size_t)sa * H_F + lane];
        float4 la = ls4[sa];
        ++jA; if (jA < r1A) sA = csr_src[jA];
        float4 ea = lexp4(la, bldA);
        denA.x += ea.x; denA.y += ea.y; denA.z += ea.z; denA.w += ea.w;
        accA.x = fmaf(ea.x, xa.x, accA.x);
        accA.y = fmaf(ea.y, xa.y, accA.y);
        accA.z = fmaf(ea.z, xa.z, accA.z);
        accA.w = fmaf(ea.w, xa.w, accA.w);
    }
    while (jB < r1B) {
        int sb = __builtin_amdgcn_readfirstlane(sB);
        float4 xb = xb4[(size_t)sb * H_F + lane];
        float4 lb = ls4[sb];
        ++jB; if (jB < r1B) sB = csr_src[jB];
        float4 eb = lexp4(lb, bldB);
        denB.x += eb.x; denB.y += eb.y; denB.z += eb.z; denB.w += eb.w;
        accB.x = fmaf(eb.x, xb.x, accB.x);
        accB.y = fmaf(eb.y, xb.y, accB.y);
        accB.z = fmaf(eb.z, xb.z, accB.z);
        accB.w = fmaf(eb.w, xb.w, accB.w);
    }

    float bv = bias[lane];
    float resA = 0.25f * (accA.x / denA.x + accA.y / denA.y +
                          accA.z / denA.z + accA.w / denA.w);
    float resB = 0.25f * (accB.x / denB.x + accB.y / denB.y +
                          accB.z / denB.z + accB.w / denB.w);
    hout[(size_t)dA * H_F + lane] = fmaxf(resA + bv, 0.f);
    hout[(size_t)dB * H_F + lane] = fmaxf(resB + bv, 0.f);
}

// ---------------- pooling (starts fused in via binary search) ----------------
__global__ void k_pool(const float* __restrict__ h, const int* __restrict__ batch,
                       float* __restrict__ pooledT) {
    int g = blockIdx.x;
    int s, e;
    {
        int lo = 0, hi = NN;
        while (lo < hi) { int mid = (lo + hi) >> 1; if (batch[mid] < g) lo = mid + 1; else hi = mid; }
        s = lo;
        lo = 0; hi = NN;
        int g1 = g + 1;
        while (lo < hi) { int mid = (lo + hi) >> 1; if (batch[mid] < g1) lo = mid + 1; else hi = mid; }
        e = lo;
    }
    int t = threadIdx.x;
    int c = t & 63, j = t >> 6;
    float sum = 0.f;
    for (int n = s + j; n < e; n += 4) sum += h[(size_t)n * H_F + c];
    __shared__ float lds[256];
    lds[t] = sum;
    __syncthreads();
    if (j == 0) {
        float tot = lds[c] + lds[64 + c] + lds[128 + c] + lds[192 + c];
        int cnt = e - s;
        float inv = 1.0f / (float)(cnt > 0 ? cnt : 1);
        pooledT[c * GG + g] = tot * inv;
    }
}

// ---------------- final FC: out[g,o] = sum_c pooledT[c][g]*Wfc[c,o] + bfc[o] --
__global__ __launch_bounds__(256) void k_fc(const float* __restrict__ pooledT,
                                            const float* __restrict__ Wfc,
                                            const float* __restrict__ bfc,
                                            float* __restrict__ out) {
    __shared__ float plds[GG * GG];   // [c][g], 16 KB
    int t = threadIdx.x;
#pragma unroll
    for (int i = 0; i < (GG * GG) / (4 * 256); ++i)   // 4 float4/thread
        ((float4*)plds)[t + 256 * i] = ((const float4*)pooledT)[t + 256 * i];
    __syncthreads();

    int o = blockIdx.x * blockDim.x + t;
    if (o >= OUT_F) return;
    float acc[GG];
#pragma unroll
    for (int g = 0; g < GG; ++g) acc[g] = 0.f;
    for (int c = 0; c < H_F; ++c) {
        float w = Wfc[(size_t)c * OUT_F + o];
        const float4* pr4 = (const float4*)(plds + c * GG);
#pragma unroll
        for (int g4 = 0; g4 < GG / 4; ++g4) {
            float4 p = pr4[g4];
            acc[4 * g4 + 0] = fmaf(p.x, w, acc[4 * g4 + 0]);
            acc[4 * g4 + 1] = fmaf(p.y, w, acc[4 * g4 + 1]);
            acc[4 * g4 + 2] = fmaf(p.z, w, acc[4 * g4 + 2]);
            acc[4 * g4 + 3] = fmaf(p.w, w, acc[4 * g4 + 3]);
        }
    }
    float bv = bfc[o];
    for (int g = 0; g < GG; ++g) out[(size_t)g * OUT_F + o] = acc[g] + bv;
}

extern "C" void kernel_launch(void* const* d_in, const int* in_sizes, int n_in,
                              void* d_out, int out_size, void* d_ws, size_t ws_size,
                              hipStream_t stream) {
    const float* x      = (const float*)d_in[0];
    const int*   eidx   = (const int*)d_in[1];
    const int*   batch  = (const int*)d_in[3];
    const float* W_emb  = (const float*)d_in[4];
    const float* b_emb  = (const float*)d_in[5];
    const float* W_fc   = (const float*)d_in[6];
    const float* b_fc   = (const float*)d_in[7];
    const float* Wl[3]   = {(const float*)d_in[8],  (const float*)d_in[12], (const float*)d_in[16]};
    const float* asl[3]  = {(const float*)d_in[9],  (const float*)d_in[13], (const float*)d_in[17]};
    const float* adl[3]  = {(const float*)d_in[10], (const float*)d_in[14], (const float*)d_in[18]};
    const float* bl[3]   = {(const float*)d_in[11], (const float*)d_in[15], (const float*)d_in[19]};

    const int* src = eidx;
    const int* dst = eidx + EE;

    // workspace carving (~82 MB)
    float* xbuf    = (float*)d_ws;                     // N*256
    float* hA      = xbuf + (size_t)NN * 256;          // N*64
    float* hB      = hA + (size_t)NN * 64;             // N*64
    float* ls      = hB + (size_t)NN * 64;             // N*4
    float* ldb     = ls + (size_t)NN * 4;              // N*4
    float* pooledT = ldb + (size_t)NN * 4;             // 64*64
    int*   cnt     = (int*)(pooledT + GG * GG);        // N
    int*   excl    = cnt + NN;                         // N
    int*   bsum    = excl + NN;                        // 256
    int*   row     = bsum + 256;                       // N+1 (pad to N+4)
    int*   cursor  = row + NN + 4;                     // N
    int*   csr_src = cursor + NN;                      // E+N

    // ---- CSR build (once; graph identical for all 3 layers) ----
    hipMemsetAsync(cnt, 0, (size_t)NN * sizeof(int), stream);
    k_count<<<(EE + NN + 255) / 256, 256, 0, stream>>>(dst, cnt);
    k_scan1<<<NBLK, SCAN_B, 0, stream>>>(cnt, excl, bsum);
    k_scan2<<<1, SCAN_B, 0, stream>>>(bsum);
    k_scan3<<<(NN + 255) / 256, 256, 0, stream>>>(excl, bsum, row, cursor);
    k_scatter<<<(EE + NN + 255) / 256, 256, 0, stream>>>(src, dst, cursor, csr_src);

    k_emb<<<(NN + 31) / 32, 256, 0, stream>>>(x, W_emb, b_emb, hA);

    float* hcur = hA;
    float* hnext = hB;
    for (int l = 0; l < 3; ++l) {
        k_gemm_layer<<<(NN + 31) / 32, 256, 0, stream>>>(hcur, Wl[l], asl[l], adl[l],
                                                         xbuf, ls, ldb);
        k_aggr_csr<<<NN / 8, 256, 0, stream>>>(row, csr_src,
                                               (const float4*)ls, (const float4*)ldb,
                                               (const float4*)xbuf, bl[l], hnext);
        float* tmp = hcur; hcur = hnext; hnext = tmp;
    }

    k_pool<<<GG, 256, 0, stream>>>(hcur, batch, pooledT);
    k_fc<<<(OUT_F + 255) / 256, 256, 0, stream>>>(pooledT, W_fc, b_fc, (float*)d_out);
}